// Round 5
// baseline (792.410 us; speedup 1.0000x reference)
//
#include <hip/hip_runtime.h>

typedef unsigned short u16;
typedef __attribute__((ext_vector_type(8))) short short8;
typedef __attribute__((ext_vector_type(4))) float f32x4;

#define B_ 2
#define N_ 16
#define T_ 512
#define D_ 512
#define H_ 8
#define DH_ 64
#define HALF_ 32
#define FF_ 828
#define FFP_ 832
#define DC_ 512
#define LN_EPS 1e-5f
#define PR_EPS 1e-8f
#define NEG_INF (-3.0e38f)

__device__ __forceinline__ float b2f(u16 u) { return __uint_as_float(((unsigned)u) << 16); }
__device__ __forceinline__ u16 f2b(float f) {
  unsigned x = __float_as_uint(f);
  return (u16)((x + 0x7fffu + ((x >> 16) & 1u)) >> 16);
}
__device__ __forceinline__ float gelu_exact(float z) {
  return 0.5f * z * (1.f + erff(z * 0.70710678118654752f));
}

typedef __attribute__((address_space(1))) const unsigned GASu;
typedef __attribute__((address_space(3))) unsigned LASu;
__device__ __forceinline__ void gload_lds16(const void* g, void* l) {
  __builtin_amdgcn_global_load_lds((GASu*)g, (LASu*)l, 16, 0, 0);
}

// ---------------- LayerNorm (+ optional gate), wave-shuffle reductions ----------------
__global__ __launch_bounds__(256) void ln_gate_kernel(
    const float* __restrict__ xsrc,
    const float* __restrict__ gate_w, const float* __restrict__ gate_b,
    const float* __restrict__ lng, const float* __restrict__ lnb,
    float* __restrict__ gate_out, u16* __restrict__ h_out, int do_gate) {
  __shared__ float redA[4], redB[4], redC[4];
  int bnt = blockIdx.x;
  int n = (bnt / T_) % N_;
  int tid = threadIdx.x;
  int lane = tid & 63, wave = tid >> 6;
  const float* xr = xsrc + (size_t)bnt * D_;
  float x0 = xr[tid], x1 = xr[tid + 256];
  float s = x0 + x1;
  #pragma unroll
  for (int off = 32; off > 0; off >>= 1) s += __shfl_xor(s, off);
  if (lane == 0) redA[wave] = s;
  if (do_gate) {
    float t = x0 * gate_w[n * D_ + tid] + x1 * gate_w[n * D_ + tid + 256];
    #pragma unroll
    for (int off = 32; off > 0; off >>= 1) t += __shfl_xor(t, off);
    if (lane == 0) redC[wave] = t;
  }
  __syncthreads();
  float mu = (redA[0] + redA[1] + redA[2] + redA[3]) * (1.f / D_);
  float d0 = x0 - mu, d1 = x1 - mu;
  float v = d0 * d0 + d1 * d1;
  #pragma unroll
  for (int off = 32; off > 0; off >>= 1) v += __shfl_xor(v, off);
  if (lane == 0) redB[wave] = v;
  __syncthreads();
  float rstd = rsqrtf((redB[0] + redB[1] + redB[2] + redB[3]) * (1.f / D_) + LN_EPS);
  if (do_gate && tid == 0)
    gate_out[bnt] = (redC[0] + redC[1] + redC[2] + redC[3] + gate_b[n] > 0.f) ? 1.f : 0.f;
  size_t o = (size_t)bnt * D_;
  h_out[o + tid]       = f2b(d0 * rstd * lng[n * D_ + tid]       + lnb[n * D_ + tid]);
  h_out[o + tid + 256] = f2b(d1 * rstd * lng[n * D_ + tid + 256] + lnb[n * D_ + tid + 256]);
}

// ---------------- weight convert+transpose: W[n][Kd][E] f32 -> Wt[n][E][Kpad] bf16 ----------------
__global__ __launch_bounds__(256) void wconv_kernel(
    const float* __restrict__ W, u16* __restrict__ Wt, int Kd, int E, int Kpad) {
  __shared__ u16 tile[32][33];
  int e0 = blockIdx.x * 32, k0 = blockIdx.y * 32, n = blockIdx.z;
  const float* Wb = W + (size_t)n * Kd * E;
  u16* Wtb = Wt + (size_t)n * E * Kpad;
  int r = threadIdx.x >> 3, c4 = (threadIdx.x & 7) * 4;
  int kk = k0 + r;
  if (kk < Kd) {
    if (e0 + c4 + 3 < E) {
      float4 w4 = *(const float4*)(Wb + (size_t)kk * E + e0 + c4);
      tile[r][c4 + 0] = f2b(w4.x); tile[r][c4 + 1] = f2b(w4.y);
      tile[r][c4 + 2] = f2b(w4.z); tile[r][c4 + 3] = f2b(w4.w);
    } else {
      #pragma unroll
      for (int j = 0; j < 4; ++j) {
        int ee = e0 + c4 + j;
        tile[r][c4 + j] = (ee < E) ? f2b(Wb[(size_t)kk * E + ee]) : (u16)0;
      }
    }
  } else {
    #pragma unroll
    for (int j = 0; j < 4; ++j) tile[r][c4 + j] = 0;
  }
  __syncthreads();
  int ee = e0 + r;
  if (ee < E) {
    u16* dst = Wtb + (size_t)ee * Kpad + k0 + c4;
    if (k0 + c4 + 3 < Kpad) {
      ushort4 o;
      o.x = tile[c4 + 0][r]; o.y = tile[c4 + 1][r];
      o.z = tile[c4 + 2][r]; o.w = tile[c4 + 3][r];
      *(ushort4*)dst = o;
    } else {
      #pragma unroll
      for (int j = 0; j < 4; ++j) if (k0 + c4 + j < Kpad) dst[j] = tile[c4 + j][r];
    }
  }
}

// ---------------- V transpose: V[bn][t][h*64+dh] -> Vt[(bn*8+h)][dh][t] (bf16) ----------------
__global__ __launch_bounds__(256) void vtrans_kernel(const u16* __restrict__ V, u16* __restrict__ Vt) {
  __shared__ u16 tile[32][36];
  int tt0 = blockIdx.x * 32;     // t tile
  int dd0 = blockIdx.y * 32;     // dh tile (0 or 32)
  int bh = blockIdx.z;           // bn*8+h
  int bn = bh >> 3, h = bh & 7;
  const u16* src = V + (size_t)bn * T_ * D_ + h * DH_;
  int r = threadIdx.x >> 3, c4 = (threadIdx.x & 7) * 4;
  *(ushort4*)&tile[r][c4] = *(const ushort4*)(src + (size_t)(tt0 + r) * D_ + dd0 + c4);
  __syncthreads();
  u16* dst = Vt + ((size_t)bh * DH_ + dd0 + r) * T_ + tt0 + c4;
  ushort4 o;
  o.x = tile[c4 + 0][r]; o.y = tile[c4 + 1][r];
  o.z = tile[c4 + 2][r]; o.w = tile[c4 + 3][r];
  *(ushort4*)dst = o;
}

// ---------------- MFMA batched per-node GEMM (double-buffered LDS) ----------------
// 2-phase pipeline: stage tile k+1 into buf^1 while computing tile k; one
// __syncthreads per K-step (its vmcnt(0) drain lands AFTER compute, not before).
#define BM 128
#define BN 128
#define BK 32
__global__ __launch_bounds__(256) void gemm_mfma_kernel(
    const u16* __restrict__ In,
    const float* __restrict__ W0, const float* __restrict__ W1, const float* __restrict__ W2,
    const u16* __restrict__ Wt0, const u16* __restrict__ Wt1, const u16* __restrict__ Wt2,
    u16* __restrict__ O0, u16* __restrict__ O1, u16* __restrict__ O2,
    float* __restrict__ OutF,
    int Kd, int KdW, int E, int Es, int mode,
    const float* __restrict__ bias,
    const float* __restrict__ xres, const float* __restrict__ gate) {
  __shared__ __align__(16) u16 As[2][BM * BK];
  __shared__ __align__(16) u16 Bs[2][BN * BK];
  int z = blockIdx.z;
  int bn = z & 31, proj = z >> 5;
  int n = bn & (N_ - 1);
  const float* W = (proj == 0) ? W0 : ((proj == 1) ? W1 : W2);
  const u16* Wt = (proj == 0) ? Wt0 : ((proj == 1) ? Wt1 : Wt2);
  u16* Out = (proj == 0) ? O0 : ((proj == 1) ? O1 : O2);
  int e0 = blockIdx.x * BN, t0 = blockIdx.y * BM;
  int tid = threadIdx.x;
  int lane = tid & 63, wave = tid >> 6;
  int m_off = (wave & 1) * 64, n_off = (wave >> 1) * 64;
  int ml = lane & 15, quad = lane >> 4;
  const u16* Inb = In + (size_t)bn * T_ * Kd;
  const float* Wb = W ? W + (size_t)n * (size_t)KdW * E : nullptr;
  const u16* Wtb = Wt ? Wt + (size_t)n * E * Kd : nullptr;

  int srow = (wave * 2) * 16 + (lane >> 2);
  int sg0 = (lane & 3) ^ ((srow >> 1) & 3);
  int sg1 = (lane & 3) ^ (((srow + 16) >> 1) & 3);
  int swz = (quad ^ ((ml >> 1) & 3)) * 8;

  auto stage = [&](u16* Ad, u16* Bd, int k0) {
    if (Wtb) {
      int i0 = wave * 2;
      gload_lds16(Inb + (size_t)(t0 + srow) * Kd + k0 + sg0 * 8, Ad + i0 * 512);
      gload_lds16(Inb + (size_t)(t0 + srow + 16) * Kd + k0 + sg1 * 8, Ad + (i0 + 1) * 512);
      gload_lds16(Wtb + (size_t)(e0 + srow) * Kd + k0 + sg0 * 8, Bd + i0 * 512);
      gload_lds16(Wtb + (size_t)(e0 + srow + 16) * Kd + k0 + sg1 * 8, Bd + (i0 + 1) * 512);
    } else {
      #pragma unroll
      for (int it = 0; it < 2; ++it) {
        int slot = tid * 2 + it;
        int r = slot >> 2;
        int q = slot & 3;
        int kg = k0 + q * 8;
        const u16* src = Inb + (size_t)(t0 + r) * Kd + kg;
        u16* dst = Ad + r * BK + (q ^ ((r >> 1) & 3)) * 8;
        if (kg + 8 <= Kd) {
          *(short8*)dst = *(const short8*)src;
        } else {
          #pragma unroll
          for (int xx = 0; xx < 8; ++xx) dst[xx] = (kg + xx < Kd) ? src[xx] : (u16)0;
        }
      }
      {
        int kk = tid & 31;
        int eb = (tid >> 5) * 16;
        int kg = k0 + kk;
        int s = kk >> 3, w = kk & 7;
        #pragma unroll
        for (int it = 0; it < 4; ++it) {
          int e = eb + it * 4;
          int eg = e0 + e;
          float4 w4 = {0.f, 0.f, 0.f, 0.f};
          if (kg < KdW && eg < E) w4 = *(const float4*)(Wb + (size_t)kg * E + eg);
          Bd[(e + 0) * BK + ((s ^ (((e + 0) >> 1) & 3)) * 8) + w] = f2b(w4.x);
          Bd[(e + 1) * BK + ((s ^ (((e + 1) >> 1) & 3)) * 8) + w] = f2b(w4.y);
          Bd[(e + 2) * BK + ((s ^ (((e + 2) >> 1) & 3)) * 8) + w] = f2b(w4.z);
          Bd[(e + 3) * BK + ((s ^ (((e + 3) >> 1) & 3)) * 8) + w] = f2b(w4.w);
        }
      }
    }
  };

  f32x4 acc[4][4] = {};

  int ksteps = (Kd + BK - 1) / BK;
  // prologue: stage tile 0 into buf 0
  stage(As[0], Bs[0], 0);
  __syncthreads();

  int cur = 0;
  for (int ks = 0; ks < ksteps; ++ks) {
    // issue next-tile loads into the other buffer (async; no wait here)
    if (ks + 1 < ksteps) stage(As[cur ^ 1], Bs[cur ^ 1], (ks + 1) * BK);
    // compute on current buffer
    short8 a[4], b[4];
    const u16* Ac = As[cur];
    const u16* Bc = Bs[cur];
    #pragma unroll
    for (int i = 0; i < 4; ++i)
      a[i] = *(const short8*)&Ac[(m_off + i * 16 + ml) * BK + swz];
    #pragma unroll
    for (int j = 0; j < 4; ++j)
      b[j] = *(const short8*)&Bc[(n_off + j * 16 + ml) * BK + swz];
    #pragma unroll
    for (int i = 0; i < 4; ++i)
      #pragma unroll
      for (int j = 0; j < 4; ++j)
        acc[i][j] = __builtin_amdgcn_mfma_f32_16x16x32_bf16(a[i], b[j], acc[i][j], 0, 0, 0);
    // vmcnt(0)+lgkmcnt(0)+barrier: prefetch landed, everyone done reading cur
    __syncthreads();
    cur ^= 1;
  }

  #pragma unroll
  for (int j = 0; j < 4; ++j) {
    int eg = e0 + n_off + j * 16 + ml;
    if (eg >= Es) continue;
    #pragma unroll
    for (int i = 0; i < 4; ++i) {
      #pragma unroll
      for (int r = 0; r < 4; ++r) {
        int tg = t0 + m_off + i * 16 + quad * 4 + r;
        float v = acc[i][j][r];
        size_t o = (size_t)bn * T_ * Es + (size_t)tg * Es + eg;
        if (mode == 0) {
          Out[o] = f2b(v);
        } else if (mode == 1) {
          float g = gate[(size_t)bn * T_ + tg];
          OutF[o] = xres[o] + v * g;
        } else if (mode == 2) {
          Out[o] = (eg < E) ? f2b(gelu_exact(v + bias[(size_t)n * E + eg])) : (u16)0;
        } else {
          Out[o] = f2b(v + bias[(size_t)n * E + eg]);
        }
      }
    }
  }
}

// ---------------- rotation + gate on Q,K; Q additionally pre-scaled by 1/8 ----------------
__global__ __launch_bounds__(256) void rot_gate_kernel(
    u16* __restrict__ q, u16* __restrict__ k,
    const float* __restrict__ phase, const float* __restrict__ gate) {
  long long i = (long long)blockIdx.x * 256 + threadIdx.x;
  int c = (int)(i & 31);
  int h = (int)((i >> 5) & 7);
  int t = (int)((i >> 8) & 511);
  int bn = (int)(i >> 17);
  int n = bn & (N_ - 1);
  float a = phase[n * H_ + h];
  float ca = cosf(a), sa = sinf(a);
  float g = gate[(size_t)bn * T_ + t];
  size_t base = ((size_t)bn * T_ + t) * D_ + h * DH_;
  float qr = b2f(q[base + c]), qi = b2f(q[base + c + HALF_]);
  u16 a0 = f2b((qr * ca - qi * sa) * g);
  u16 a1 = f2b((qr * sa + qi * ca) * g);
  q[base + c]         = f2b(b2f(a0) * 0.125f);
  q[base + c + HALF_] = f2b(b2f(a1) * 0.125f);
  float kr = b2f(k[base + c]), ki = b2f(k[base + c + HALF_]);
  k[base + c]         = f2b((kr * ca - ki * sa) * g);
  k[base + c + HALF_] = f2b((kr * sa + ki * ca) * g);
}

// ---------------- MFMA flash attention ----------------
#define ATS 72
__global__ __launch_bounds__(256) void attn_kernel(
    const u16* __restrict__ Q, const u16* __restrict__ K, const u16* __restrict__ V,
    const u16* __restrict__ Vt, u16* __restrict__ O) {
  __shared__ __align__(16) u16 Qs[64 * ATS];
  __shared__ __align__(16) u16 Ks[64 * ATS];
  __shared__ __align__(16) u16 Vs[64 * ATS];   // transposed: Vs[d][s]
  __shared__ __align__(16) u16 Ps[64 * ATS];   // wave-private row strips
  int qt = blockIdx.x, h = blockIdx.y, bn = blockIdx.z;
  int tid = threadIdx.x;
  int lane = tid & 63, wave = tid >> 6;
  int ml = lane & 15, quad = lane >> 4;
  int t0 = qt * 64;
  size_t rowbase = (size_t)bn * T_ * D_ + (size_t)h * DH_;
  int r = tid >> 2;              // row 0..63
  int c = (tid & 3) * 16;        // col base 0/16/32/48

  {
    const u16* src = Q + rowbase + (size_t)(t0 + r) * D_ + c;
    *(short8*)&Qs[r * ATS + c]     = *(const short8*)(src);
    *(short8*)&Qs[r * ATS + c + 8] = *(const short8*)(src + 8);
  }
  const u16* ksrc = K + rowbase + (size_t)r * D_ + c;
  const u16* vsrc = Vt ? (Vt + ((size_t)(bn * H_ + h) * DH_ + r) * T_ + c) : nullptr;

  float m_[4], l_[4];
  f32x4 acco[4] = {};
  #pragma unroll
  for (int rr = 0; rr < 4; ++rr) { m_[rr] = NEG_INF; l_[rr] = 0.f; }

  for (int sc = 0; sc < 8; ++sc) {
    int s0 = sc * 64;
    {
      const u16* kp = ksrc + (size_t)s0 * D_;
      *(short8*)&Ks[r * ATS + c]     = *(const short8*)(kp);
      *(short8*)&Ks[r * ATS + c + 8] = *(const short8*)(kp + 8);
    }
    if (Vt) {
      const u16* vp = vsrc + s0;
      *(short8*)&Vs[r * ATS + c]     = *(const short8*)(vp);
      *(short8*)&Vs[r * ATS + c + 8] = *(const short8*)(vp + 8);
    } else {
      int sw = wave * 16;
      const u16* src = V + rowbase + (size_t)(s0 + sw) * D_ + lane;
      short8 v0, v1;
      #pragma unroll
      for (int rr = 0; rr < 8; ++rr) ((u16*)&v0)[rr] = src[(size_t)rr * D_];
      #pragma unroll
      for (int rr = 0; rr < 8; ++rr) ((u16*)&v1)[rr] = src[(size_t)(rr + 8) * D_];
      *(short8*)&Vs[lane * ATS + sw]     = v0;
      *(short8*)&Vs[lane * ATS + sw + 8] = v1;
    }
    __syncthreads();

    f32x4 s4[4] = {};
    #pragma unroll
    for (int kst = 0; kst < 2; ++kst) {
      short8 a = *(const short8*)&Qs[(wave * 16 + ml) * ATS + kst * 32 + quad * 8];
      #pragma unroll
      for (int j = 0; j < 4; ++j) {
        short8 b = *(const short8*)&Ks[(j * 16 + ml) * ATS + kst * 32 + quad * 8];
        s4[j] = __builtin_amdgcn_mfma_f32_16x16x32_bf16(a, b, s4[j], 0, 0, 0);
      }
    }

    #pragma unroll
    for (int rr = 0; rr < 4; ++rr) {
      float cm = fmaxf(fmaxf(s4[0][rr], s4[1][rr]), fmaxf(s4[2][rr], s4[3][rr]));
      #pragma unroll
      for (int off = 1; off < 16; off <<= 1) cm = fmaxf(cm, __shfl_xor(cm, off));
      if (cm > m_[rr]) {
        float al = __expf(m_[rr] - cm);
        l_[rr] *= al;
        #pragma unroll
        for (int jd = 0; jd < 4; ++jd) acco[jd][rr] *= al;
        m_[rr] = cm;
      }
      u16 q0 = f2b(__expf(s4[0][rr] - m_[rr])), q1 = f2b(__expf(s4[1][rr] - m_[rr]));
      u16 q2 = f2b(__expf(s4[2][rr] - m_[rr])), q3 = f2b(__expf(s4[3][rr] - m_[rr]));
      float rs = b2f(q0) + b2f(q1) + b2f(q2) + b2f(q3);
      #pragma unroll
      for (int off = 1; off < 16; off <<= 1) rs += __shfl_xor(rs, off);
      l_[rr] += rs;
      int trow = wave * 16 + quad * 4 + rr;
      Ps[trow * ATS + 0 * 16 + ml] = q0;
      Ps[trow * ATS + 1 * 16 + ml] = q1;
      Ps[trow * ATS + 2 * 16 + ml] = q2;
      Ps[trow * ATS + 3 * 16 + ml] = q3;
    }

    #pragma unroll
    for (int sst = 0; sst < 2; ++sst) {
      short8 a = *(const short8*)&Ps[(wave * 16 + ml) * ATS + sst * 32 + quad * 8];
      #pragma unroll
      for (int jd = 0; jd < 4; ++jd) {
        short8 b = *(const short8*)&Vs[(jd * 16 + ml) * ATS + sst * 32 + quad * 8];
        acco[jd] = __builtin_amdgcn_mfma_f32_16x16x32_bf16(a, b, acco[jd], 0, 0, 0);
      }
    }
    __syncthreads();
  }

  #pragma unroll
  for (int rr = 0; rr < 4; ++rr) {
    float inv = 1.f / l_[rr];
    int trow = t0 + wave * 16 + quad * 4 + rr;
    #pragma unroll
    for (int jd = 0; jd < 4; ++jd)
      O[rowbase + (size_t)trow * D_ + jd * 16 + ml] = f2b(acco[jd][rr] * inv);
  }
}

// ---------------- pooling (split for parallelism) ----------------
__global__ __launch_bounds__(256) void pool1_kernel(const float* __restrict__ x2, float* __restrict__ part) {
  int tc = blockIdx.x & 15, bn = blockIdx.x >> 4;
  int d = threadIdx.x;
  const float* base = x2 + ((size_t)bn * T_ + tc * 32) * D_;
  float s0 = 0.f, s1 = 0.f;
  for (int t = 0; t < 32; ++t) {
    s0 += base[(size_t)t * D_ + d];
    s1 += base[(size_t)t * D_ + d + 256];
  }
  float* p = part + ((size_t)bn * 16 + tc) * D_;
  p[d] = s0; p[d + 256] = s1;
}
__global__ __launch_bounds__(256) void pool2_kernel(const float* __restrict__ part, float* __restrict__ cp) {
  int bn = blockIdx.x;
  int d = threadIdx.x;
  float s0 = 0.f, s1 = 0.f;
  for (int tc = 0; tc < 16; ++tc) {
    s0 += part[((size_t)bn * 16 + tc) * D_ + d];
    s1 += part[((size_t)bn * 16 + tc) * D_ + d + 256];
  }
  cp[(size_t)bn * D_ + d]       = s0 * (1.f / T_);
  cp[(size_t)bn * D_ + d + 256] = s1 * (1.f / T_);
}

__global__ __launch_bounds__(256) void commit_center_kernel(
    const float* __restrict__ cp, const float* __restrict__ commit_w, const float* __restrict__ commit_b,
    const float* __restrict__ center_w, const float* __restrict__ center_b,
    float* __restrict__ commit, float* __restrict__ center) {
  __shared__ float cps[512];
  __shared__ float red[256];
  int bn = blockIdx.x, n = bn % N_, tid = threadIdx.x;
  cps[tid] = cp[(size_t)bn * D_ + tid];
  cps[tid + 256] = cp[(size_t)bn * D_ + tid + 256];
  __syncthreads();
  red[tid] = cps[tid] * commit_w[n * D_ + tid] + cps[tid + 256] * commit_w[n * D_ + tid + 256];
  __syncthreads();
  for (int s = 128; s > 0; s >>= 1) { if (tid < s) red[tid] += red[tid + s]; __syncthreads(); }
  if (tid == 0) commit[bn] = 1.f / (1.f + expf(-(red[0] + commit_b[n])));
  #pragma unroll
  for (int eo = 0; eo < 2; ++eo) {
    int e = eo * 256 + tid;
    float acc = center_b[(size_t)n * DC_ + e];
    for (int d = 0; d < D_; ++d) acc = fmaf(cps[d], center_w[((size_t)n * D_ + d) * DC_ + e], acc);
    center[(size_t)bn * DC_ + e] = tanhf(acc);
  }
}

__global__ __launch_bounds__(256) void matvec_kernel(
    const float* __restrict__ inp, const float* __restrict__ Wm, float* __restrict__ outp) {
  __shared__ float s[512];
  int bn = blockIdx.x, tid = threadIdx.x;
  s[tid] = inp[(size_t)bn * D_ + tid];
  s[tid + 256] = inp[(size_t)bn * D_ + tid + 256];
  __syncthreads();
  #pragma unroll
  for (int eo = 0; eo < 2; ++eo) {
    int e = eo * 256 + tid;
    float acc = 0.f;
    for (int d = 0; d < D_; ++d) acc = fmaf(s[d], Wm[(size_t)d * D_ + e], acc);
    outp[(size_t)bn * D_ + e] = acc;
  }
}

__global__ __launch_bounds__(256) void uv_kernel(
    const float* __restrict__ hres, float* __restrict__ u, float* __restrict__ v) {
  int i = blockIdx.x * 256 + threadIdx.x;
  float xr = hres[2 * i] + PR_EPS;
  float yi = hres[2 * i + 1] + PR_EPS;
  float r = sqrtf(xr * xr + yi * yi);
  u[i] = xr / r; v[i] = yi / r;
}

__global__ __launch_bounds__(256) void racc_kernel(
    const float* __restrict__ u, const float* __restrict__ v, float* __restrict__ ra) {
  int b = blockIdx.x, tid = threadIdx.x;
  int mm = tid >> 4, nn = tid & 15;
  const float* ub = u + (size_t)b * N_ * 256;
  const float* vb = v + (size_t)b * N_ * 256;
  float acc = 0.f;
  for (int p = 0; p < 256; ++p)
    acc += ub[mm * 256 + p] * ub[nn * 256 + p] + vb[mm * 256 + p] * vb[nn * 256 + p];
  ra[(size_t)b * N_ * N_ + mm * N_ + nn] = acc * (1.f / 256.f);
}

__global__ __launch_bounds__(256) void recv_kernel(
    const float* __restrict__ ra, const float* __restrict__ commit,
    const float* __restrict__ hres, const float* __restrict__ cond, float* __restrict__ recv) {
  int bn = blockIdx.x, b = bn / N_, mm = bn % N_, tid = threadIdx.x;
  float c = cond[0];
  #pragma unroll
  for (int eo = 0; eo < 2; ++eo) {
    int d = eo * 256 + tid;
    float acc = 0.f;
    for (int nn = 0; nn < N_; ++nn)
      acc += ra[(size_t)b * N_ * N_ + mm * N_ + nn] * commit[b * N_ + nn] *
             hres[((size_t)b * N_ + nn) * D_ + d];
    recv[(size_t)bn * D_ + d] = c * acc;
  }
}

__global__ __launch_bounds__(256) void final_kernel(
    const float* __restrict__ x2, const float* __restrict__ commit,
    const float* __restrict__ gate, const u16* __restrict__ ff,
    const float* __restrict__ fs, float* __restrict__ out) {
  long long i4 = (long long)blockIdx.x * 256 + threadIdx.x;
  long long base = i4 * 4;
  int d = (int)(base & (D_ - 1));
  int t = (int)((base >> 9) & (T_ - 1));
  int bn = (int)(base >> 18);
  float cg = commit[bn] * gate[(size_t)bn * T_ + t];
  float4 xv = *(const float4*)(x2 + base);
  ushort4 fv = *(const ushort4*)(ff + base);
  float4 sv = *(const float4*)(fs + (size_t)bn * D_ + d);
  float4 r;
  r.x = xv.x + cg * b2f(fv.x) + sv.x;
  r.y = xv.y + cg * b2f(fv.y) + sv.y;
  r.z = xv.z + cg * b2f(fv.z) + sv.z;
  r.w = xv.w + cg * b2f(fv.w) + sv.w;
  *(float4*)(out + base) = r;
}

extern "C" void kernel_launch(void* const* d_in, const int* in_sizes, int n_in,
                              void* d_out, int out_size, void* d_ws, size_t ws_size,
                              hipStream_t stream) {
  (void)in_sizes; (void)n_in; (void)out_size;
  const float* x          = (const float*)d_in[0];
  const float* gate_w     = (const float*)d_in[1];
  const float* gate_b     = (const float*)d_in[2];
  const float* ln1_g      = (const float*)d_in[3];
  const float* ln1_b      = (const float*)d_in[4];
  const float* wq         = (const float*)d_in[5];
  const float* wk         = (const float*)d_in[6];
  const float* wv         = (const float*)d_in[7];
  const float* wo         = (const float*)d_in[8];
  const float* phase      = (const float*)d_in[9];
  const float* ln2_g      = (const float*)d_in[10];
  const float* ln2_b      = (const float*)d_in[11];
  const float* up_w       = (const float*)d_in[12];
  const float* up_b       = (const float*)d_in[13];
  const float* down_w     = (const float*)d_in[14];
  const float* down_b     = (const float*)d_in[15];
  const float* commit_w   = (const float*)d_in[16];
  const float* commit_b   = (const float*)d_in[17];
  const float* center_w   = (const float*)d_in[18];
  const float* center_b   = (const float*)d_in[19];
  const float* field_in_w = (const float*)d_in[20];
  const float* field_out_w= (const float*)d_in[21];
  const float* cond       = (const float*)d_in[22];

  const long long BNTD = 8388608LL;     // 2*16*512*512
  u16* w16 = (u16*)d_ws;
  u16* R0 = w16;               // h -> attnout -> ff
  u16* R1 = w16 + BNTD;        // Q -> h2
  u16* R2 = w16 + 2 * BNTD;    // K -> up (stride 832, spills into R3)
  u16* R3 = w16 + 3 * BNTD;    // V
  float* sm   = (float*)(w16 + 4 * BNTD);
  float* gate   = sm;
  float* cp     = sm + 16384;
  float* center = sm + 2 * 16384;
  float* hres   = sm + 3 * 16384;
  float* uu     = sm + 4 * 16384;
  float* vv     = uu + 8192;
  float* ra     = vv + 8192;
  float* recvb  = ra + 512;
  float* fsig   = recvb + 16384;
  float* commit = fsig + 16384;
  float* part   = sm + 115232;           // 32*16*512 f32 = 262144
  float* x2 = (float*)d_out;

  // ---- converted weights (bf16 transposed) + Vt in ws tail ----
  const size_t WSQ = (size_t)N_ * 512 * 512;
  const size_t WUPu = (size_t)N_ * 828 * 512;
  const size_t WUPd = (size_t)N_ * 512 * 832;
  u16* wtbase = (u16*)(sm + 115232 + 262144);
  u16* wtq = wtbase;
  u16* wtk = wtq + WSQ;
  u16* wtv = wtk + WSQ;
  u16* wto = wtv + WSQ;
  u16* wtu = wto + WSQ;
  u16* wtd = wtu + WUPu;
  u16* vtb = wtd + WUPd;                 // Vt: [bn*8+h][64][512] u16
  size_t needed = (size_t)((char*)(vtb + BNTD) - (char*)d_ws);
  bool use_wt = ws_size >= needed;

  ln_gate_kernel<<<16384, 256, 0, stream>>>(x, gate_w, gate_b, ln1_g, ln1_b, gate, R0, 1);

  if (use_wt) {
    wconv_kernel<<<dim3(16, 16, 16), 256, 0, stream>>>(wq, wtq, 512, 512, 512);
    wconv_kernel<<<dim3(16, 16, 16), 256, 0, stream>>>(wk, wtk, 512, 512, 512);
    wconv_kernel<<<dim3(16, 16, 16), 256, 0, stream>>>(wv, wtv, 512, 512, 512);
    wconv_kernel<<<dim3(16, 16, 16), 256, 0, stream>>>(wo, wto, 512, 512, 512);
    wconv_kernel<<<dim3(26, 16, 16), 256, 0, stream>>>(up_w, wtu, 512, 828, 512);
    wconv_kernel<<<dim3(16, 26, 16), 256, 0, stream>>>(down_w, wtd, 828, 512, 832);
  }
  const u16* pq = use_wt ? wtq : nullptr;
  const u16* pk = use_wt ? wtk : nullptr;
  const u16* pv = use_wt ? wtv : nullptr;
  const u16* po = use_wt ? wto : nullptr;
  const u16* pu = use_wt ? wtu : nullptr;
  const u16* pd = use_wt ? wtd : nullptr;

  gemm_mfma_kernel<<<dim3(4, 4, 96), 256, 0, stream>>>(
      R0, wq, wk, wv, pq, pk, pv, R1, R2, R3, nullptr,
      512, 512, 512, 512, 0, nullptr, nullptr, nullptr);
  rot_gate_kernel<<<16384, 256, 0, stream>>>(R1, R2, phase, gate);
  if (use_wt) vtrans_kernel<<<dim3(16, 2, 256), 256, 0, stream>>>(R3, vtb);
  attn_kernel<<<dim3(8, 8, 32), 256, 0, stream>>>(R1, R2, R3, use_wt ? vtb : nullptr, R0);
  gemm_mfma_kernel<<<dim3(4, 4, 32), 256, 0, stream>>>(
      R0, wo, nullptr, nullptr, po, nullptr, nullptr, nullptr, nullptr, nullptr, x2,
      512, 512, 512, 512, 1, nullptr, x, gate);
  ln_gate_kernel<<<16384, 256, 0, stream>>>(x2, nullptr, nullptr, ln2_g, ln2_b, nullptr, R1, 0);
  gemm_mfma_kernel<<<dim3(7, 4, 32), 256, 0, stream>>>(
      R1, up_w, nullptr, nullptr, pu, nullptr, nullptr, R2, nullptr, nullptr, nullptr,
      512, 512, 828, 832, 2, up_b, nullptr, nullptr);
  gemm_mfma_kernel<<<dim3(4, 4, 32), 256, 0, stream>>>(
      R2, down_w, nullptr, nullptr, pd, nullptr, nullptr, R0, nullptr, nullptr, nullptr,
      832, 828, 512, 512, 3, down_b, nullptr, nullptr);
  pool1_kernel<<<512, 256, 0, stream>>>(x2, part);
  pool2_kernel<<<32, 256, 0, stream>>>(part, cp);
  commit_center_kernel<<<32, 256, 0, stream>>>(cp, commit_w, commit_b, center_w, center_b, commit, center);
  matvec_kernel<<<32, 256, 0, stream>>>(center, field_in_w, hres);
  uv_kernel<<<32, 256, 0, stream>>>(hres, uu, vv);
  racc_kernel<<<2, 256, 0, stream>>>(uu, vv, ra);
  recv_kernel<<<32, 256, 0, stream>>>(ra, commit, hres, cond, recvb);
  matvec_kernel<<<32, 256, 0, stream>>>(recvb, field_out_w, fsig);
  final_kernel<<<8192, 256, 0, stream>>>(x2, commit, gate, R0, fsig, x2);
}

// Round 6
// 780.405 us; speedup vs baseline: 1.0154x; 1.0154x over previous
//
#include <hip/hip_runtime.h>

typedef unsigned short u16;
typedef __attribute__((ext_vector_type(8))) short short8;
typedef __attribute__((ext_vector_type(4))) float f32x4;

#define B_ 2
#define N_ 16
#define T_ 512
#define D_ 512
#define H_ 8
#define DH_ 64
#define HALF_ 32
#define FF_ 828
#define FFP_ 832
#define DC_ 512
#define LN_EPS 1e-5f
#define PR_EPS 1e-8f
#define NEG_INF (-3.0e38f)

__device__ __forceinline__ float b2f(u16 u) { return __uint_as_float(((unsigned)u) << 16); }
__device__ __forceinline__ u16 f2b(float f) {
  unsigned x = __float_as_uint(f);
  return (u16)((x + 0x7fffu + ((x >> 16) & 1u)) >> 16);
}
__device__ __forceinline__ float gelu_exact(float z) {
  return 0.5f * z * (1.f + erff(z * 0.70710678118654752f));
}

typedef __attribute__((address_space(1))) const unsigned GASu;
typedef __attribute__((address_space(3))) unsigned LASu;
__device__ __forceinline__ void gload_lds16(const void* g, void* l) {
  __builtin_amdgcn_global_load_lds((GASu*)g, (LASu*)l, 16, 0, 0);
}

// ---------------- LayerNorm (+ optional gate), wave-shuffle reductions ----------------
__global__ __launch_bounds__(256) void ln_gate_kernel(
    const float* __restrict__ xsrc,
    const float* __restrict__ gate_w, const float* __restrict__ gate_b,
    const float* __restrict__ lng, const float* __restrict__ lnb,
    float* __restrict__ gate_out, u16* __restrict__ h_out, int do_gate) {
  __shared__ float redA[4], redB[4], redC[4];
  int bnt = blockIdx.x;
  int n = (bnt / T_) % N_;
  int tid = threadIdx.x;
  int lane = tid & 63, wave = tid >> 6;
  const float* xr = xsrc + (size_t)bnt * D_;
  float x0 = xr[tid], x1 = xr[tid + 256];
  float s = x0 + x1;
  #pragma unroll
  for (int off = 32; off > 0; off >>= 1) s += __shfl_xor(s, off);
  if (lane == 0) redA[wave] = s;
  if (do_gate) {
    float t = x0 * gate_w[n * D_ + tid] + x1 * gate_w[n * D_ + tid + 256];
    #pragma unroll
    for (int off = 32; off > 0; off >>= 1) t += __shfl_xor(t, off);
    if (lane == 0) redC[wave] = t;
  }
  __syncthreads();
  float mu = (redA[0] + redA[1] + redA[2] + redA[3]) * (1.f / D_);
  float d0 = x0 - mu, d1 = x1 - mu;
  float v = d0 * d0 + d1 * d1;
  #pragma unroll
  for (int off = 32; off > 0; off >>= 1) v += __shfl_xor(v, off);
  if (lane == 0) redB[wave] = v;
  __syncthreads();
  float rstd = rsqrtf((redB[0] + redB[1] + redB[2] + redB[3]) * (1.f / D_) + LN_EPS);
  if (do_gate && tid == 0)
    gate_out[bnt] = (redC[0] + redC[1] + redC[2] + redC[3] + gate_b[n] > 0.f) ? 1.f : 0.f;
  size_t o = (size_t)bnt * D_;
  h_out[o + tid]       = f2b(d0 * rstd * lng[n * D_ + tid]       + lnb[n * D_ + tid]);
  h_out[o + tid + 256] = f2b(d1 * rstd * lng[n * D_ + tid + 256] + lnb[n * D_ + tid + 256]);
}

// ---------------- weight convert+transpose: W[n][Kd][E] f32 -> Wt[n][E][Kpad] bf16 ----------------
__global__ __launch_bounds__(256) void wconv_kernel(
    const float* __restrict__ W, u16* __restrict__ Wt, int Kd, int E, int Kpad) {
  __shared__ u16 tile[32][33];
  int e0 = blockIdx.x * 32, k0 = blockIdx.y * 32, n = blockIdx.z;
  const float* Wb = W + (size_t)n * Kd * E;
  u16* Wtb = Wt + (size_t)n * E * Kpad;
  int r = threadIdx.x >> 3, c4 = (threadIdx.x & 7) * 4;
  int kk = k0 + r;
  if (kk < Kd) {
    if (e0 + c4 + 3 < E) {
      float4 w4 = *(const float4*)(Wb + (size_t)kk * E + e0 + c4);
      tile[r][c4 + 0] = f2b(w4.x); tile[r][c4 + 1] = f2b(w4.y);
      tile[r][c4 + 2] = f2b(w4.z); tile[r][c4 + 3] = f2b(w4.w);
    } else {
      #pragma unroll
      for (int j = 0; j < 4; ++j) {
        int ee = e0 + c4 + j;
        tile[r][c4 + j] = (ee < E) ? f2b(Wb[(size_t)kk * E + ee]) : (u16)0;
      }
    }
  } else {
    #pragma unroll
    for (int j = 0; j < 4; ++j) tile[r][c4 + j] = 0;
  }
  __syncthreads();
  int ee = e0 + r;
  if (ee < E) {
    u16* dst = Wtb + (size_t)ee * Kpad + k0 + c4;
    if (k0 + c4 + 3 < Kpad) {
      ushort4 o;
      o.x = tile[c4 + 0][r]; o.y = tile[c4 + 1][r];
      o.z = tile[c4 + 2][r]; o.w = tile[c4 + 3][r];
      *(ushort4*)dst = o;
    } else {
      #pragma unroll
      for (int j = 0; j < 4; ++j) if (k0 + c4 + j < Kpad) dst[j] = tile[c4 + j][r];
    }
  }
}

// ---------------- V transpose: V[bn][t][h*64+dh] -> Vt[(bn*8+h)][dh][t] (bf16) ----------------
__global__ __launch_bounds__(256) void vtrans_kernel(const u16* __restrict__ V, u16* __restrict__ Vt) {
  __shared__ u16 tile[32][36];
  int tt0 = blockIdx.x * 32;     // t tile
  int dd0 = blockIdx.y * 32;     // dh tile (0 or 32)
  int bh = blockIdx.z;           // bn*8+h
  int bn = bh >> 3, h = bh & 7;
  const u16* src = V + (size_t)bn * T_ * D_ + h * DH_;
  int r = threadIdx.x >> 3, c4 = (threadIdx.x & 7) * 4;
  *(ushort4*)&tile[r][c4] = *(const ushort4*)(src + (size_t)(tt0 + r) * D_ + dd0 + c4);
  __syncthreads();
  u16* dst = Vt + ((size_t)bh * DH_ + dd0 + r) * T_ + tt0 + c4;
  ushort4 o;
  o.x = tile[c4 + 0][r]; o.y = tile[c4 + 1][r];
  o.z = tile[c4 + 2][r]; o.w = tile[c4 + 3][r];
  *(ushort4*)dst = o;
}

// ---------------- MFMA batched per-node GEMM (single buffer, BK=64) ----------------
// LDS [128][64] bf16 per operand; logical 16B chunk c of row r lives at
// position c^(r&7) (full 8-way bank spread). Staged via global_load_lds:
// lane l covers row r0+(l>>3), phys chunk l&7, logical chunk (l&7)^(l>>3).
// Read: phys chunk = (kst*4+quad) ^ (ml&7)  (2 lanes / 16B column = free).
#define BM 128
#define BN 128
#define BK 64
__global__ __launch_bounds__(256) void gemm_mfma_kernel(
    const u16* __restrict__ In,
    const float* __restrict__ W0, const float* __restrict__ W1, const float* __restrict__ W2,
    const u16* __restrict__ Wt0, const u16* __restrict__ Wt1, const u16* __restrict__ Wt2,
    u16* __restrict__ O0, u16* __restrict__ O1, u16* __restrict__ O2,
    float* __restrict__ OutF,
    int Kd, int KdW, int E, int Es, int mode,
    const float* __restrict__ bias,
    const float* __restrict__ xres, const float* __restrict__ gate) {
  __shared__ __align__(16) u16 As[BM * BK];
  __shared__ __align__(16) u16 Bs[BN * BK];
  int z = blockIdx.z;
  int bn = z & 31, proj = z >> 5;
  int n = bn & (N_ - 1);
  const float* W = (proj == 0) ? W0 : ((proj == 1) ? W1 : W2);
  const u16* Wt = (proj == 0) ? Wt0 : ((proj == 1) ? Wt1 : Wt2);
  u16* Out = (proj == 0) ? O0 : ((proj == 1) ? O1 : O2);
  int e0 = blockIdx.x * BN, t0 = blockIdx.y * BM;
  int tid = threadIdx.x;
  int lane = tid & 63, wave = tid >> 6;
  int m_off = (wave & 1) * 64, n_off = (wave >> 1) * 64;
  int ml = lane & 15, quad = lane >> 4;
  const u16* Inb = In + (size_t)bn * T_ * Kd;
  const float* Wb = W ? W + (size_t)n * (size_t)KdW * E : nullptr;
  const u16* Wtb = Wt ? Wt + (size_t)n * E * Kd : nullptr;

  int lrow = lane >> 3;                    // 0..7
  int lchunk = ((lane & 7) ^ lrow) * 8;    // logical chunk offset (u16)

  f32x4 acc[4][4] = {};

  int ksteps = (Kd + BK - 1) / BK;
  for (int ks = 0; ks < ksteps; ++ks) {
    int k0 = ks * BK;
    if (Wtb) {
      #pragma unroll
      for (int it = 0; it < 4; ++it) {
        int r0 = wave * 32 + it * 8;
        gload_lds16(Inb + (size_t)(t0 + r0 + lrow) * Kd + k0 + lchunk, &As[r0 * BK]);
        gload_lds16(Wtb + (size_t)(e0 + r0 + lrow) * Kd + k0 + lchunk, &Bs[r0 * BK]);
      }
    } else {
      // fallback: scalar staging (correctness path; wt path is the fast one)
      #pragma unroll
      for (int it = 0; it < 4; ++it) {
        int cid = tid * 4 + it;          // 0..1023
        int r = cid >> 3, cp = cid & 7;
        int clog = cp ^ (r & 7);
        int kg = k0 + clog * 8;
        u16* dst = &As[r * BK + cp * 8];
        const u16* src = Inb + (size_t)(t0 + r) * Kd + kg;
        if (kg + 8 <= Kd) {
          *(short8*)dst = *(const short8*)src;
        } else {
          #pragma unroll
          for (int xx = 0; xx < 8; ++xx) dst[xx] = (kg + xx < Kd) ? src[xx] : (u16)0;
        }
        int eg = e0 + r;
        u16* bdst = &Bs[r * BK + cp * 8];
        #pragma unroll
        for (int xx = 0; xx < 8; ++xx)
          bdst[xx] = (kg + xx < KdW && eg < E) ? f2b(Wb[(size_t)(kg + xx) * E + eg]) : (u16)0;
      }
    }
    __syncthreads();
    #pragma unroll
    for (int kst = 0; kst < 2; ++kst) {
      int so = ((kst * 4 + quad) ^ (ml & 7)) * 8;
      short8 a[4], b[4];
      #pragma unroll
      for (int i = 0; i < 4; ++i)
        a[i] = *(const short8*)&As[(m_off + i * 16 + ml) * BK + so];
      #pragma unroll
      for (int j = 0; j < 4; ++j)
        b[j] = *(const short8*)&Bs[(n_off + j * 16 + ml) * BK + so];
      #pragma unroll
      for (int i = 0; i < 4; ++i)
        #pragma unroll
        for (int j = 0; j < 4; ++j)
          acc[i][j] = __builtin_amdgcn_mfma_f32_16x16x32_bf16(a[i], b[j], acc[i][j], 0, 0, 0);
    }
    __syncthreads();
  }

  #pragma unroll
  for (int j = 0; j < 4; ++j) {
    int eg = e0 + n_off + j * 16 + ml;
    if (eg >= Es) continue;
    #pragma unroll
    for (int i = 0; i < 4; ++i) {
      #pragma unroll
      for (int r = 0; r < 4; ++r) {
        int tg = t0 + m_off + i * 16 + quad * 4 + r;
        float v = acc[i][j][r];
        size_t o = (size_t)bn * T_ * Es + (size_t)tg * Es + eg;
        if (mode == 0) {
          Out[o] = f2b(v);
        } else if (mode == 1) {
          float g = gate[(size_t)bn * T_ + tg];
          OutF[o] = xres[o] + v * g;
        } else if (mode == 2) {
          Out[o] = (eg < E) ? f2b(gelu_exact(v + bias[(size_t)n * E + eg])) : (u16)0;
        } else {
          Out[o] = f2b(v + bias[(size_t)n * E + eg]);
        }
      }
    }
  }
}

// ---------------- rotation + gate on Q,K; Q additionally pre-scaled by 1/8 ----------------
__global__ __launch_bounds__(256) void rot_gate_kernel(
    u16* __restrict__ q, u16* __restrict__ k,
    const float* __restrict__ phase, const float* __restrict__ gate) {
  long long i = (long long)blockIdx.x * 256 + threadIdx.x;
  int c = (int)(i & 31);
  int h = (int)((i >> 5) & 7);
  int t = (int)((i >> 8) & 511);
  int bn = (int)(i >> 17);
  int n = bn & (N_ - 1);
  float a = phase[n * H_ + h];
  float ca = cosf(a), sa = sinf(a);
  float g = gate[(size_t)bn * T_ + t];
  size_t base = ((size_t)bn * T_ + t) * D_ + h * DH_;
  float qr = b2f(q[base + c]), qi = b2f(q[base + c + HALF_]);
  u16 a0 = f2b((qr * ca - qi * sa) * g);
  u16 a1 = f2b((qr * sa + qi * ca) * g);
  q[base + c]         = f2b(b2f(a0) * 0.125f);
  q[base + c + HALF_] = f2b(b2f(a1) * 0.125f);
  float kr = b2f(k[base + c]), ki = b2f(k[base + c + HALF_]);
  k[base + c]         = f2b((kr * ca - ki * sa) * g);
  k[base + c + HALF_] = f2b((kr * sa + ki * ca) * g);
}

// ---------------- MFMA flash attention ----------------
#define ATS 72
__global__ __launch_bounds__(256) void attn_kernel(
    const u16* __restrict__ Q, const u16* __restrict__ K, const u16* __restrict__ V,
    const u16* __restrict__ Vt, u16* __restrict__ O) {
  __shared__ __align__(16) u16 Qs[64 * ATS];
  __shared__ __align__(16) u16 Ks[64 * ATS];
  __shared__ __align__(16) u16 Vs[64 * ATS];   // transposed: Vs[d][s]
  __shared__ __align__(16) u16 Ps[64 * ATS];   // wave-private row strips
  int qt = blockIdx.x, h = blockIdx.y, bn = blockIdx.z;
  int tid = threadIdx.x;
  int lane = tid & 63, wave = tid >> 6;
  int ml = lane & 15, quad = lane >> 4;
  int t0 = qt * 64;
  size_t rowbase = (size_t)bn * T_ * D_ + (size_t)h * DH_;
  int r = tid >> 2;              // row 0..63
  int c = (tid & 3) * 16;        // col base 0/16/32/48

  {
    const u16* src = Q + rowbase + (size_t)(t0 + r) * D_ + c;
    *(short8*)&Qs[r * ATS + c]     = *(const short8*)(src);
    *(short8*)&Qs[r * ATS + c + 8] = *(const short8*)(src + 8);
  }
  const u16* ksrc = K + rowbase + (size_t)r * D_ + c;
  const u16* vsrc = Vt ? (Vt + ((size_t)(bn * H_ + h) * DH_ + r) * T_ + c) : nullptr;

  float m_[4], l_[4];
  f32x4 acco[4] = {};
  #pragma unroll
  for (int rr = 0; rr < 4; ++rr) { m_[rr] = NEG_INF; l_[rr] = 0.f; }

  for (int sc = 0; sc < 8; ++sc) {
    int s0 = sc * 64;
    {
      const u16* kp = ksrc + (size_t)s0 * D_;
      *(short8*)&Ks[r * ATS + c]     = *(const short8*)(kp);
      *(short8*)&Ks[r * ATS + c + 8] = *(const short8*)(kp + 8);
    }
    if (Vt) {
      const u16* vp = vsrc + s0;
      *(short8*)&Vs[r * ATS + c]     = *(const short8*)(vp);
      *(short8*)&Vs[r * ATS + c + 8] = *(const short8*)(vp + 8);
    } else {
      int sw = wave * 16;
      const u16* src = V + rowbase + (size_t)(s0 + sw) * D_ + lane;
      short8 v0, v1;
      #pragma unroll
      for (int rr = 0; rr < 8; ++rr) ((u16*)&v0)[rr] = src[(size_t)rr * D_];
      #pragma unroll
      for (int rr = 0; rr < 8; ++rr) ((u16*)&v1)[rr] = src[(size_t)(rr + 8) * D_];
      *(short8*)&Vs[lane * ATS + sw]     = v0;
      *(short8*)&Vs[lane * ATS + sw + 8] = v1;
    }
    __syncthreads();

    f32x4 s4[4] = {};
    #pragma unroll
    for (int kst = 0; kst < 2; ++kst) {
      short8 a = *(const short8*)&Qs[(wave * 16 + ml) * ATS + kst * 32 + quad * 8];
      #pragma unroll
      for (int j = 0; j < 4; ++j) {
        short8 b = *(const short8*)&Ks[(j * 16 + ml) * ATS + kst * 32 + quad * 8];
        s4[j] = __builtin_amdgcn_mfma_f32_16x16x32_bf16(a, b, s4[j], 0, 0, 0);
      }
    }

    #pragma unroll
    for (int rr = 0; rr < 4; ++rr) {
      float cm = fmaxf(fmaxf(s4[0][rr], s4[1][rr]), fmaxf(s4[2][rr], s4[3][rr]));
      #pragma unroll
      for (int off = 1; off < 16; off <<= 1) cm = fmaxf(cm, __shfl_xor(cm, off));
      if (cm > m_[rr]) {
        float al = __expf(m_[rr] - cm);
        l_[rr] *= al;
        #pragma unroll
        for (int jd = 0; jd < 4; ++jd) acco[jd][rr] *= al;
        m_[rr] = cm;
      }
      u16 q0 = f2b(__expf(s4[0][rr] - m_[rr])), q1 = f2b(__expf(s4[1][rr] - m_[rr]));
      u16 q2 = f2b(__expf(s4[2][rr] - m_[rr])), q3 = f2b(__expf(s4[3][rr] - m_[rr]));
      float rs = b2f(q0) + b2f(q1) + b2f(q2) + b2f(q3);
      #pragma unroll
      for (int off = 1; off < 16; off <<= 1) rs += __shfl_xor(rs, off);
      l_[rr] += rs;
      int trow = wave * 16 + quad * 4 + rr;
      Ps[trow * ATS + 0 * 16 + ml] = q0;
      Ps[trow * ATS + 1 * 16 + ml] = q1;
      Ps[trow * ATS + 2 * 16 + ml] = q2;
      Ps[trow * ATS + 3 * 16 + ml] = q3;
    }

    #pragma unroll
    for (int sst = 0; sst < 2; ++sst) {
      short8 a = *(const short8*)&Ps[(wave * 16 + ml) * ATS + sst * 32 + quad * 8];
      #pragma unroll
      for (int jd = 0; jd < 4; ++jd) {
        short8 b = *(const short8*)&Vs[(jd * 16 + ml) * ATS + sst * 32 + quad * 8];
        acco[jd] = __builtin_amdgcn_mfma_f32_16x16x32_bf16(a, b, acco[jd], 0, 0, 0);
      }
    }
    __syncthreads();
  }

  #pragma unroll
  for (int rr = 0; rr < 4; ++rr) {
    float inv = 1.f / l_[rr];
    int trow = t0 + wave * 16 + quad * 4 + rr;
    #pragma unroll
    for (int jd = 0; jd < 4; ++jd)
      O[rowbase + (size_t)trow * D_ + jd * 16 + ml] = f2b(acco[jd][rr] * inv);
  }
}

// ---------------- pooling (split for parallelism) ----------------
__global__ __launch_bounds__(256) void pool1_kernel(const float* __restrict__ x2, float* __restrict__ part) {
  int tc = blockIdx.x & 15, bn = blockIdx.x >> 4;
  int d = threadIdx.x;
  const float* base = x2 + ((size_t)bn * T_ + tc * 32) * D_;
  float s0 = 0.f, s1 = 0.f;
  for (int t = 0; t < 32; ++t) {
    s0 += base[(size_t)t * D_ + d];
    s1 += base[(size_t)t * D_ + d + 256];
  }
  float* p = part + ((size_t)bn * 16 + tc) * D_;
  p[d] = s0; p[d + 256] = s1;
}
__global__ __launch_bounds__(256) void pool2_kernel(const float* __restrict__ part, float* __restrict__ cp) {
  int bn = blockIdx.x;
  int d = threadIdx.x;
  float s0 = 0.f, s1 = 0.f;
  for (int tc = 0; tc < 16; ++tc) {
    s0 += part[((size_t)bn * 16 + tc) * D_ + d];
    s1 += part[((size_t)bn * 16 + tc) * D_ + d + 256];
  }
  cp[(size_t)bn * D_ + d]       = s0 * (1.f / T_);
  cp[(size_t)bn * D_ + d + 256] = s1 * (1.f / T_);
}

__global__ __launch_bounds__(256) void commit_center_kernel(
    const float* __restrict__ cp, const float* __restrict__ commit_w, const float* __restrict__ commit_b,
    const float* __restrict__ center_w, const float* __restrict__ center_b,
    float* __restrict__ commit, float* __restrict__ center) {
  __shared__ float cps[512];
  __shared__ float red[256];
  int bn = blockIdx.x, n = bn % N_, tid = threadIdx.x;
  cps[tid] = cp[(size_t)bn * D_ + tid];
  cps[tid + 256] = cp[(size_t)bn * D_ + tid + 256];
  __syncthreads();
  red[tid] = cps[tid] * commit_w[n * D_ + tid] + cps[tid + 256] * commit_w[n * D_ + tid + 256];
  __syncthreads();
  for (int s = 128; s > 0; s >>= 1) { if (tid < s) red[tid] += red[tid + s]; __syncthreads(); }
  if (tid == 0) commit[bn] = 1.f / (1.f + expf(-(red[0] + commit_b[n])));
  #pragma unroll
  for (int eo = 0; eo < 2; ++eo) {
    int e = eo * 256 + tid;
    float acc = center_b[(size_t)n * DC_ + e];
    for (int d = 0; d < D_; ++d) acc = fmaf(cps[d], center_w[((size_t)n * D_ + d) * DC_ + e], acc);
    center[(size_t)bn * DC_ + e] = tanhf(acc);
  }
}

__global__ __launch_bounds__(256) void matvec_kernel(
    const float* __restrict__ inp, const float* __restrict__ Wm, float* __restrict__ outp) {
  __shared__ float s[512];
  int bn = blockIdx.x, tid = threadIdx.x;
  s[tid] = inp[(size_t)bn * D_ + tid];
  s[tid + 256] = inp[(size_t)bn * D_ + tid + 256];
  __syncthreads();
  #pragma unroll
  for (int eo = 0; eo < 2; ++eo) {
    int e = eo * 256 + tid;
    float acc = 0.f;
    for (int d = 0; d < D_; ++d) acc = fmaf(s[d], Wm[(size_t)d * D_ + e], acc);
    outp[(size_t)bn * D_ + e] = acc;
  }
}

__global__ __launch_bounds__(256) void uv_kernel(
    const float* __restrict__ hres, float* __restrict__ u, float* __restrict__ v) {
  int i = blockIdx.x * 256 + threadIdx.x;
  float xr = hres[2 * i] + PR_EPS;
  float yi = hres[2 * i + 1] + PR_EPS;
  float r = sqrtf(xr * xr + yi * yi);
  u[i] = xr / r; v[i] = yi / r;
}

__global__ __launch_bounds__(256) void racc_kernel(
    const float* __restrict__ u, const float* __restrict__ v, float* __restrict__ ra) {
  int b = blockIdx.x, tid = threadIdx.x;
  int mm = tid >> 4, nn = tid & 15;
  const float* ub = u + (size_t)b * N_ * 256;
  const float* vb = v + (size_t)b * N_ * 256;
  float acc = 0.f;
  for (int p = 0; p < 256; ++p)
    acc += ub[mm * 256 + p] * ub[nn * 256 + p] + vb[mm * 256 + p] * vb[nn * 256 + p];
  ra[(size_t)b * N_ * N_ + mm * N_ + nn] = acc * (1.f / 256.f);
}

__global__ __launch_bounds__(256) void recv_kernel(
    const float* __restrict__ ra, const float* __restrict__ commit,
    const float* __restrict__ hres, const float* __restrict__ cond, float* __restrict__ recv) {
  int bn = blockIdx.x, b = bn / N_, mm = bn % N_, tid = threadIdx.x;
  float c = cond[0];
  #pragma unroll
  for (int eo = 0; eo < 2; ++eo) {
    int d = eo * 256 + tid;
    float acc = 0.f;
    for (int nn = 0; nn < N_; ++nn)
      acc += ra[(size_t)b * N_ * N_ + mm * N_ + nn] * commit[b * N_ + nn] *
             hres[((size_t)b * N_ + nn) * D_ + d];
    recv[(size_t)bn * D_ + d] = c * acc;
  }
}

__global__ __launch_bounds__(256) void final_kernel(
    const float* __restrict__ x2, const float* __restrict__ commit,
    const float* __restrict__ gate, const u16* __restrict__ ff,
    const float* __restrict__ fs, float* __restrict__ out) {
  long long i4 = (long long)blockIdx.x * 256 + threadIdx.x;
  long long base = i4 * 4;
  int d = (int)(base & (D_ - 1));
  int t = (int)((base >> 9) & (T_ - 1));
  int bn = (int)(base >> 18);
  float cg = commit[bn] * gate[(size_t)bn * T_ + t];
  float4 xv = *(const float4*)(x2 + base);
  ushort4 fv = *(const ushort4*)(ff + base);
  float4 sv = *(const float4*)(fs + (size_t)bn * D_ + d);
  float4 r;
  r.x = xv.x + cg * b2f(fv.x) + sv.x;
  r.y = xv.y + cg * b2f(fv.y) + sv.y;
  r.z = xv.z + cg * b2f(fv.z) + sv.z;
  r.w = xv.w + cg * b2f(fv.w) + sv.w;
  *(float4*)(out + base) = r;
}

extern "C" void kernel_launch(void* const* d_in, const int* in_sizes, int n_in,
                              void* d_out, int out_size, void* d_ws, size_t ws_size,
                              hipStream_t stream) {
  (void)in_sizes; (void)n_in; (void)out_size;
  const float* x          = (const float*)d_in[0];
  const float* gate_w     = (const float*)d_in[1];
  const float* gate_b     = (const float*)d_in[2];
  const float* ln1_g      = (const float*)d_in[3];
  const float* ln1_b      = (const float*)d_in[4];
  const float* wq         = (const float*)d_in[5];
  const float* wk         = (const float*)d_in[6];
  const float* wv         = (const float*)d_in[7];
  const float* wo         = (const float*)d_in[8];
  const float* phase      = (const float*)d_in[9];
  const float* ln2_g      = (const float*)d_in[10];
  const float* ln2_b      = (const float*)d_in[11];
  const float* up_w       = (const float*)d_in[12];
  const float* up_b       = (const float*)d_in[13];
  const float* down_w     = (const float*)d_in[14];
  const float* down_b     = (const float*)d_in[15];
  const float* commit_w   = (const float*)d_in[16];
  const float* commit_b   = (const float*)d_in[17];
  const float* center_w   = (const float*)d_in[18];
  const float* center_b   = (const float*)d_in[19];
  const float* field_in_w = (const float*)d_in[20];
  const float* field_out_w= (const float*)d_in[21];
  const float* cond       = (const float*)d_in[22];

  const long long BNTD = 8388608LL;     // 2*16*512*512
  u16* w16 = (u16*)d_ws;
  u16* R0 = w16;               // h -> attnout -> ff
  u16* R1 = w16 + BNTD;        // Q -> h2
  u16* R2 = w16 + 2 * BNTD;    // K -> up (stride 832, spills into R3)
  u16* R3 = w16 + 3 * BNTD;    // V
  float* sm   = (float*)(w16 + 4 * BNTD);
  float* gate   = sm;
  float* cp     = sm + 16384;
  float* center = sm + 2 * 16384;
  float* hres   = sm + 3 * 16384;
  float* uu     = sm + 4 * 16384;
  float* vv     = uu + 8192;
  float* ra     = vv + 8192;
  float* recvb  = ra + 512;
  float* fsig   = recvb + 16384;
  float* commit = fsig + 16384;
  float* part   = sm + 115232;           // 32*16*512 f32 = 262144
  float* x2 = (float*)d_out;

  // ---- converted weights (bf16 transposed) + Vt in ws tail ----
  const size_t WSQ = (size_t)N_ * 512 * 512;
  const size_t WUPu = (size_t)N_ * 828 * 512;
  const size_t WUPd = (size_t)N_ * 512 * 832;
  u16* wtbase = (u16*)(sm + 115232 + 262144);
  u16* wtq = wtbase;
  u16* wtk = wtq + WSQ;
  u16* wtv = wtk + WSQ;
  u16* wto = wtv + WSQ;
  u16* wtu = wto + WSQ;
  u16* wtd = wtu + WUPu;
  u16* vtb = wtd + WUPd;                 // Vt: [bn*8+h][64][512] u16
  size_t needed = (size_t)((char*)(vtb + BNTD) - (char*)d_ws);
  bool use_wt = ws_size >= needed;

  ln_gate_kernel<<<16384, 256, 0, stream>>>(x, gate_w, gate_b, ln1_g, ln1_b, gate, R0, 1);

  if (use_wt) {
    wconv_kernel<<<dim3(16, 16, 16), 256, 0, stream>>>(wq, wtq, 512, 512, 512);
    wconv_kernel<<<dim3(16, 16, 16), 256, 0, stream>>>(wk, wtk, 512, 512, 512);
    wconv_kernel<<<dim3(16, 16, 16), 256, 0, stream>>>(wv, wtv, 512, 512, 512);
    wconv_kernel<<<dim3(16, 16, 16), 256, 0, stream>>>(wo, wto, 512, 512, 512);
    wconv_kernel<<<dim3(26, 16, 16), 256, 0, stream>>>(up_w, wtu, 512, 828, 512);
    wconv_kernel<<<dim3(16, 26, 16), 256, 0, stream>>>(down_w, wtd, 828, 512, 832);
  }
  const u16* pq = use_wt ? wtq : nullptr;
  const u16* pk = use_wt ? wtk : nullptr;
  const u16* pv = use_wt ? wtv : nullptr;
  const u16* po = use_wt ? wto : nullptr;
  const u16* pu = use_wt ? wtu : nullptr;
  const u16* pd = use_wt ? wtd : nullptr;

  gemm_mfma_kernel<<<dim3(4, 4, 96), 256, 0, stream>>>(
      R0, wq, wk, wv, pq, pk, pv, R1, R2, R3, nullptr,
      512, 512, 512, 512, 0, nullptr, nullptr, nullptr);
  rot_gate_kernel<<<16384, 256, 0, stream>>>(R1, R2, phase, gate);
  if (use_wt) vtrans_kernel<<<dim3(16, 2, 256), 256, 0, stream>>>(R3, vtb);
  attn_kernel<<<dim3(8, 8, 32), 256, 0, stream>>>(R1, R2, R3, use_wt ? vtb : nullptr, R0);
  gemm_mfma_kernel<<<dim3(4, 4, 32), 256, 0, stream>>>(
      R0, wo, nullptr, nullptr, po, nullptr, nullptr, nullptr, nullptr, nullptr, x2,
      512, 512, 512, 512, 1, nullptr, x, gate);
  ln_gate_kernel<<<16384, 256, 0, stream>>>(x2, nullptr, nullptr, ln2_g, ln2_b, nullptr, R1, 0);
  gemm_mfma_kernel<<<dim3(7, 4, 32), 256, 0, stream>>>(
      R1, up_w, nullptr, nullptr, pu, nullptr, nullptr, R2, nullptr, nullptr, nullptr,
      512, 512, 828, 832, 2, up_b, nullptr, nullptr);
  gemm_mfma_kernel<<<dim3(4, 4, 32), 256, 0, stream>>>(
      R2, down_w, nullptr, nullptr, pd, nullptr, nullptr, R0, nullptr, nullptr, nullptr,
      832, 828, 512, 512, 3, down_b, nullptr, nullptr);
  pool1_kernel<<<512, 256, 0, stream>>>(x2, part);
  pool2_kernel<<<32, 256, 0, stream>>>(part, cp);
  commit_center_kernel<<<32, 256, 0, stream>>>(cp, commit_w, commit_b, center_w, center_b, commit, center);
  matvec_kernel<<<32, 256, 0, stream>>>(center, field_in_w, hres);
  uv_kernel<<<32, 256, 0, stream>>>(hres, uu, vv);
  racc_kernel<<<2, 256, 0, stream>>>(uu, vv, ra);
  recv_kernel<<<32, 256, 0, stream>>>(ra, commit, hres, cond, recvb);
  matvec_kernel<<<32, 256, 0, stream>>>(recvb, field_out_w, fsig);
  final_kernel<<<8192, 256, 0, stream>>>(x2, commit, gate, R0, fsig, x2);
}

// Round 7
// 743.319 us; speedup vs baseline: 1.0660x; 1.0499x over previous
//
#include <hip/hip_runtime.h>

typedef unsigned short u16;
typedef __attribute__((ext_vector_type(8))) short short8;
typedef __attribute__((ext_vector_type(4))) float f32x4;

#define B_ 2
#define N_ 16
#define T_ 512
#define D_ 512
#define H_ 8
#define DH_ 64
#define HALF_ 32
#define FF_ 828
#define FFP_ 832
#define DC_ 512
#define LN_EPS 1e-5f
#define PR_EPS 1e-8f
#define NEG_INF (-3.0e38f)

__device__ __forceinline__ float b2f(u16 u) { return __uint_as_float(((unsigned)u) << 16); }
__device__ __forceinline__ u16 f2b(float f) {
  unsigned x = __float_as_uint(f);
  return (u16)((x + 0x7fffu + ((x >> 16) & 1u)) >> 16);
}
__device__ __forceinline__ float gelu_exact(float z) {
  return 0.5f * z * (1.f + erff(z * 0.70710678118654752f));
}

typedef __attribute__((address_space(1))) const unsigned GASu;
typedef __attribute__((address_space(3))) unsigned LASu;
__device__ __forceinline__ void gload_lds16(const void* g, void* l) {
  __builtin_amdgcn_global_load_lds((GASu*)g, (LASu*)l, 16, 0, 0);
}

// ---------------- LayerNorm (+ optional gate), wave-shuffle reductions ----------------
__global__ __launch_bounds__(256) void ln_gate_kernel(
    const float* __restrict__ xsrc,
    const float* __restrict__ gate_w, const float* __restrict__ gate_b,
    const float* __restrict__ lng, const float* __restrict__ lnb,
    float* __restrict__ gate_out, u16* __restrict__ h_out, int do_gate) {
  __shared__ float redA[4], redB[4], redC[4];
  int bnt = blockIdx.x;
  int n = (bnt / T_) % N_;
  int tid = threadIdx.x;
  int lane = tid & 63, wave = tid >> 6;
  const float* xr = xsrc + (size_t)bnt * D_;
  float x0 = xr[tid], x1 = xr[tid + 256];
  float s = x0 + x1;
  #pragma unroll
  for (int off = 32; off > 0; off >>= 1) s += __shfl_xor(s, off);
  if (lane == 0) redA[wave] = s;
  if (do_gate) {
    float t = x0 * gate_w[n * D_ + tid] + x1 * gate_w[n * D_ + tid + 256];
    #pragma unroll
    for (int off = 32; off > 0; off >>= 1) t += __shfl_xor(t, off);
    if (lane == 0) redC[wave] = t;
  }
  __syncthreads();
  float mu = (redA[0] + redA[1] + redA[2] + redA[3]) * (1.f / D_);
  float d0 = x0 - mu, d1 = x1 - mu;
  float v = d0 * d0 + d1 * d1;
  #pragma unroll
  for (int off = 32; off > 0; off >>= 1) v += __shfl_xor(v, off);
  if (lane == 0) redB[wave] = v;
  __syncthreads();
  float rstd = rsqrtf((redB[0] + redB[1] + redB[2] + redB[3]) * (1.f / D_) + LN_EPS);
  if (do_gate && tid == 0)
    gate_out[bnt] = (redC[0] + redC[1] + redC[2] + redC[3] + gate_b[n] > 0.f) ? 1.f : 0.f;
  size_t o = (size_t)bnt * D_;
  h_out[o + tid]       = f2b(d0 * rstd * lng[n * D_ + tid]       + lnb[n * D_ + tid]);
  h_out[o + tid + 256] = f2b(d1 * rstd * lng[n * D_ + tid + 256] + lnb[n * D_ + tid + 256]);
}

// ---------------- weight convert+transpose: W[n][Kd][E] f32 -> Wt[n][E][Kpad] bf16 ----------------
__global__ __launch_bounds__(256) void wconv_kernel(
    const float* __restrict__ W, u16* __restrict__ Wt, int Kd, int E, int Kpad) {
  __shared__ u16 tile[32][33];
  int e0 = blockIdx.x * 32, k0 = blockIdx.y * 32, n = blockIdx.z;
  const float* Wb = W + (size_t)n * Kd * E;
  u16* Wtb = Wt + (size_t)n * E * Kpad;
  int r = threadIdx.x >> 3, c4 = (threadIdx.x & 7) * 4;
  int kk = k0 + r;
  if (kk < Kd) {
    if (e0 + c4 + 3 < E) {
      float4 w4 = *(const float4*)(Wb + (size_t)kk * E + e0 + c4);
      tile[r][c4 + 0] = f2b(w4.x); tile[r][c4 + 1] = f2b(w4.y);
      tile[r][c4 + 2] = f2b(w4.z); tile[r][c4 + 3] = f2b(w4.w);
    } else {
      #pragma unroll
      for (int j = 0; j < 4; ++j) {
        int ee = e0 + c4 + j;
        tile[r][c4 + j] = (ee < E) ? f2b(Wb[(size_t)kk * E + ee]) : (u16)0;
      }
    }
  } else {
    #pragma unroll
    for (int j = 0; j < 4; ++j) tile[r][c4 + j] = 0;
  }
  __syncthreads();
  int ee = e0 + r;
  if (ee < E) {
    u16* dst = Wtb + (size_t)ee * Kpad + k0 + c4;
    if (k0 + c4 + 3 < Kpad) {
      ushort4 o;
      o.x = tile[c4 + 0][r]; o.y = tile[c4 + 1][r];
      o.z = tile[c4 + 2][r]; o.w = tile[c4 + 3][r];
      *(ushort4*)dst = o;
    } else {
      #pragma unroll
      for (int j = 0; j < 4; ++j) if (k0 + c4 + j < Kpad) dst[j] = tile[c4 + j][r];
    }
  }
}

// ---------------- V transpose: V[bn][t][h*64+dh] -> Vt[(bn*8+h)][dh][t] (bf16) ----------------
__global__ __launch_bounds__(256) void vtrans_kernel(const u16* __restrict__ V, u16* __restrict__ Vt) {
  __shared__ u16 tile[32][36];
  int tt0 = blockIdx.x * 32;     // t tile
  int dd0 = blockIdx.y * 32;     // dh tile (0 or 32)
  int bh = blockIdx.z;           // bn*8+h
  int bn = bh >> 3, h = bh & 7;
  const u16* src = V + (size_t)bn * T_ * D_ + h * DH_;
  int r = threadIdx.x >> 3, c4 = (threadIdx.x & 7) * 4;
  *(ushort4*)&tile[r][c4] = *(const ushort4*)(src + (size_t)(tt0 + r) * D_ + dd0 + c4);
  __syncthreads();
  u16* dst = Vt + ((size_t)bh * DH_ + dd0 + r) * T_ + tt0 + c4;
  ushort4 o;
  o.x = tile[c4 + 0][r]; o.y = tile[c4 + 1][r];
  o.z = tile[c4 + 2][r]; o.w = tile[c4 + 3][r];
  *(ushort4*)dst = o;
}

// ---------------- MFMA batched per-node GEMM (BK=64, XCD-chunked swizzle) ----------------
// 1D grid; launched id L: xcd=L&7 (HW round-robin), slot=L>>3. XCD k owns
// z in [k*zPerXcd, (k+1)*zPerXcd) -> all xy-blocks of a z co-reside on one XCD,
// its L2 absorbs the 16x In-reuse and 4x weight-panel-reuse.
// doRot: QKV fusion -- proj0=Q rotate+gate+1/8, proj1=K rotate+gate, proj2=V plain.
// Rotation is bit-exact vs separate kernel: round proj to bf16 first, rotate in
// f32, round; Q extra *0.125 (exact pow2) with its own round.
#define BM 128
#define BN 128
#define BK 64
__global__ __launch_bounds__(256) void gemm_mfma_kernel(
    const u16* __restrict__ In,
    const float* __restrict__ W0, const float* __restrict__ W1, const float* __restrict__ W2,
    const u16* __restrict__ Wt0, const u16* __restrict__ Wt1, const u16* __restrict__ Wt2,
    u16* __restrict__ O0, u16* __restrict__ O1, u16* __restrict__ O2,
    float* __restrict__ OutF,
    int Kd, int KdW, int E, int Es, int mode,
    const float* __restrict__ bias,
    const float* __restrict__ xres, const float* __restrict__ gate,
    const float* __restrict__ phase, int doRot,
    int xdim, int nXY, int zPerXcd) {
  __shared__ __align__(16) u16 As[BM * BK];
  __shared__ __align__(16) u16 Bs[BN * BK];
  int L = blockIdx.x;
  int xcd = L & 7, slot = L >> 3;
  int zloc = slot / nXY, xy = slot - zloc * nXY;
  int z = xcd * zPerXcd + zloc;
  int bx = xy % xdim, by = xy / xdim;
  int bn = z & 31, proj = z >> 5;
  int n = bn & (N_ - 1);
  const float* W = (proj == 0) ? W0 : ((proj == 1) ? W1 : W2);
  const u16* Wt = (proj == 0) ? Wt0 : ((proj == 1) ? Wt1 : Wt2);
  u16* Out = (proj == 0) ? O0 : ((proj == 1) ? O1 : O2);
  int e0 = bx * BN, t0 = by * BM;
  int tid = threadIdx.x;
  int lane = tid & 63, wave = tid >> 6;
  int m_off = (wave & 1) * 64, n_off = (wave >> 1) * 64;
  int ml = lane & 15, quad = lane >> 4;
  const u16* Inb = In + (size_t)bn * T_ * Kd;
  const float* Wb = W ? W + (size_t)n * (size_t)KdW * E : nullptr;
  const u16* Wtb = Wt ? Wt + (size_t)n * E * Kd : nullptr;

  int lrow = lane >> 3;                    // 0..7
  int lchunk = ((lane & 7) ^ lrow) * 8;    // logical chunk offset (u16)

  f32x4 acc[4][4] = {};

  int ksteps = (Kd + BK - 1) / BK;
  for (int ks = 0; ks < ksteps; ++ks) {
    int k0 = ks * BK;
    if (Wtb) {
      #pragma unroll
      for (int it = 0; it < 4; ++it) {
        int r0 = wave * 32 + it * 8;
        gload_lds16(Inb + (size_t)(t0 + r0 + lrow) * Kd + k0 + lchunk, &As[r0 * BK]);
        gload_lds16(Wtb + (size_t)(e0 + r0 + lrow) * Kd + k0 + lchunk, &Bs[r0 * BK]);
      }
    } else {
      // fallback: scalar staging (correctness path; wt path is the fast one)
      #pragma unroll
      for (int it = 0; it < 4; ++it) {
        int cid = tid * 4 + it;          // 0..1023
        int r = cid >> 3, cp = cid & 7;
        int clog = cp ^ (r & 7);
        int kg = k0 + clog * 8;
        u16* dst = &As[r * BK + cp * 8];
        const u16* src = Inb + (size_t)(t0 + r) * Kd + kg;
        if (kg + 8 <= Kd) {
          *(short8*)dst = *(const short8*)src;
        } else {
          #pragma unroll
          for (int xx = 0; xx < 8; ++xx) dst[xx] = (kg + xx < Kd) ? src[xx] : (u16)0;
        }
        int eg = e0 + r;
        u16* bdst = &Bs[r * BK + cp * 8];
        #pragma unroll
        for (int xx = 0; xx < 8; ++xx)
          bdst[xx] = (kg + xx < KdW && eg < E) ? f2b(Wb[(size_t)(kg + xx) * E + eg]) : (u16)0;
      }
    }
    __syncthreads();
    #pragma unroll
    for (int kst = 0; kst < 2; ++kst) {
      int so = ((kst * 4 + quad) ^ (ml & 7)) * 8;
      short8 a[4], b[4];
      #pragma unroll
      for (int i = 0; i < 4; ++i)
        a[i] = *(const short8*)&As[(m_off + i * 16 + ml) * BK + so];
      #pragma unroll
      for (int j = 0; j < 4; ++j)
        b[j] = *(const short8*)&Bs[(n_off + j * 16 + ml) * BK + so];
      #pragma unroll
      for (int i = 0; i < 4; ++i)
        #pragma unroll
        for (int j = 0; j < 4; ++j)
          acc[i][j] = __builtin_amdgcn_mfma_f32_16x16x32_bf16(a[i], b[j], acc[i][j], 0, 0, 0);
    }
    __syncthreads();
  }

  int rmode = doRot ? ((proj == 0) ? 2 : ((proj == 1) ? 1 : 0)) : 0;
  if (rmode) {
    // head index is wave-uniform: hc = j*16+ml < 64
    int h = (e0 + n_off) >> 6;
    float ang = phase[n * H_ + h];
    float ca = cosf(ang), sa = sinf(ang);
    #pragma unroll
    for (int i = 0; i < 4; ++i) {
      #pragma unroll
      for (int r = 0; r < 4; ++r) {
        int tg = t0 + m_off + i * 16 + quad * 4 + r;
        float g = gate[(size_t)bn * T_ + tg];
        #pragma unroll
        for (int j = 0; j < 2; ++j) {
          int eg = e0 + n_off + j * 16 + ml;
          size_t o = (size_t)bn * T_ * Es + (size_t)tg * Es + eg;
          float re = b2f(f2b(acc[i][j][r]));
          float im = b2f(f2b(acc[i][j + 2][r]));
          u16 a0 = f2b((re * ca - im * sa) * g);
          u16 a1 = f2b((re * sa + im * ca) * g);
          if (rmode == 2) { a0 = f2b(b2f(a0) * 0.125f); a1 = f2b(b2f(a1) * 0.125f); }
          Out[o] = a0;
          Out[o + 32] = a1;
        }
      }
    }
  } else {
    #pragma unroll
    for (int j = 0; j < 4; ++j) {
      int eg = e0 + n_off + j * 16 + ml;
      if (eg >= Es) continue;
      #pragma unroll
      for (int i = 0; i < 4; ++i) {
        #pragma unroll
        for (int r = 0; r < 4; ++r) {
          int tg = t0 + m_off + i * 16 + quad * 4 + r;
          float v = acc[i][j][r];
          size_t o = (size_t)bn * T_ * Es + (size_t)tg * Es + eg;
          if (mode == 0) {
            Out[o] = f2b(v);
          } else if (mode == 1) {
            float g = gate[(size_t)bn * T_ + tg];
            OutF[o] = xres[o] + v * g;
          } else if (mode == 2) {
            Out[o] = (eg < E) ? f2b(gelu_exact(v + bias[(size_t)n * E + eg])) : (u16)0;
          } else {
            Out[o] = f2b(v + bias[(size_t)n * E + eg]);
          }
        }
      }
    }
  }
}

// ---------------- MFMA flash attention ----------------
#define ATS 72
__global__ __launch_bounds__(256) void attn_kernel(
    const u16* __restrict__ Q, const u16* __restrict__ K, const u16* __restrict__ V,
    const u16* __restrict__ Vt, u16* __restrict__ O) {
  __shared__ __align__(16) u16 Qs[64 * ATS];
  __shared__ __align__(16) u16 Ks[64 * ATS];
  __shared__ __align__(16) u16 Vs[64 * ATS];   // transposed: Vs[d][s]
  __shared__ __align__(16) u16 Ps[64 * ATS];   // wave-private row strips
  int qt = blockIdx.x, h = blockIdx.y, bn = blockIdx.z;
  int tid = threadIdx.x;
  int lane = tid & 63, wave = tid >> 6;
  int ml = lane & 15, quad = lane >> 4;
  int t0 = qt * 64;
  size_t rowbase = (size_t)bn * T_ * D_ + (size_t)h * DH_;
  int r = tid >> 2;              // row 0..63
  int c = (tid & 3) * 16;        // col base 0/16/32/48

  {
    const u16* src = Q + rowbase + (size_t)(t0 + r) * D_ + c;
    *(short8*)&Qs[r * ATS + c]     = *(const short8*)(src);
    *(short8*)&Qs[r * ATS + c + 8] = *(const short8*)(src + 8);
  }
  const u16* ksrc = K + rowbase + (size_t)r * D_ + c;
  const u16* vsrc = Vt ? (Vt + ((size_t)(bn * H_ + h) * DH_ + r) * T_ + c) : nullptr;

  float m_[4], l_[4];
  f32x4 acco[4] = {};
  #pragma unroll
  for (int rr = 0; rr < 4; ++rr) { m_[rr] = NEG_INF; l_[rr] = 0.f; }

  for (int sc = 0; sc < 8; ++sc) {
    int s0 = sc * 64;
    {
      const u16* kp = ksrc + (size_t)s0 * D_;
      *(short8*)&Ks[r * ATS + c]     = *(const short8*)(kp);
      *(short8*)&Ks[r * ATS + c + 8] = *(const short8*)(kp + 8);
    }
    if (Vt) {
      const u16* vp = vsrc + s0;
      *(short8*)&Vs[r * ATS + c]     = *(const short8*)(vp);
      *(short8*)&Vs[r * ATS + c + 8] = *(const short8*)(vp + 8);
    } else {
      int sw = wave * 16;
      const u16* src = V + rowbase + (size_t)(s0 + sw) * D_ + lane;
      short8 v0, v1;
      #pragma unroll
      for (int rr = 0; rr < 8; ++rr) ((u16*)&v0)[rr] = src[(size_t)rr * D_];
      #pragma unroll
      for (int rr = 0; rr < 8; ++rr) ((u16*)&v1)[rr] = src[(size_t)(rr + 8) * D_];
      *(short8*)&Vs[lane * ATS + sw]     = v0;
      *(short8*)&Vs[lane * ATS + sw + 8] = v1;
    }
    __syncthreads();

    f32x4 s4[4] = {};
    #pragma unroll
    for (int kst = 0; kst < 2; ++kst) {
      short8 a = *(const short8*)&Qs[(wave * 16 + ml) * ATS + kst * 32 + quad * 8];
      #pragma unroll
      for (int j = 0; j < 4; ++j) {
        short8 b = *(const short8*)&Ks[(j * 16 + ml) * ATS + kst * 32 + quad * 8];
        s4[j] = __builtin_amdgcn_mfma_f32_16x16x32_bf16(a, b, s4[j], 0, 0, 0);
      }
    }

    #pragma unroll
    for (int rr = 0; rr < 4; ++rr) {
      float cm = fmaxf(fmaxf(s4[0][rr], s4[1][rr]), fmaxf(s4[2][rr], s4[3][rr]));
      #pragma unroll
      for (int off = 1; off < 16; off <<= 1) cm = fmaxf(cm, __shfl_xor(cm, off));
      if (cm > m_[rr]) {
        float al = __expf(m_[rr] - cm);
        l_[rr] *= al;
        #pragma unroll
        for (int jd = 0; jd < 4; ++jd) acco[jd][rr] *= al;
        m_[rr] = cm;
      }
      u16 q0 = f2b(__expf(s4[0][rr] - m_[rr])), q1 = f2b(__expf(s4[1][rr] - m_[rr]));
      u16 q2 = f2b(__expf(s4[2][rr] - m_[rr])), q3 = f2b(__expf(s4[3][rr] - m_[rr]));
      float rs = b2f(q0) + b2f(q1) + b2f(q2) + b2f(q3);
      #pragma unroll
      for (int off = 1; off < 16; off <<= 1) rs += __shfl_xor(rs, off);
      l_[rr] += rs;
      int trow = wave * 16 + quad * 4 + rr;
      Ps[trow * ATS + 0 * 16 + ml] = q0;
      Ps[trow * ATS + 1 * 16 + ml] = q1;
      Ps[trow * ATS + 2 * 16 + ml] = q2;
      Ps[trow * ATS + 3 * 16 + ml] = q3;
    }

    #pragma unroll
    for (int sst = 0; sst < 2; ++sst) {
      short8 a = *(const short8*)&Ps[(wave * 16 + ml) * ATS + sst * 32 + quad * 8];
      #pragma unroll
      for (int jd = 0; jd < 4; ++jd) {
        short8 b = *(const short8*)&Vs[(jd * 16 + ml) * ATS + sst * 32 + quad * 8];
        acco[jd] = __builtin_amdgcn_mfma_f32_16x16x32_bf16(a, b, acco[jd], 0, 0, 0);
      }
    }
    __syncthreads();
  }

  #pragma unroll
  for (int rr = 0; rr < 4; ++rr) {
    float inv = 1.f / l_[rr];
    int trow = t0 + wave * 16 + quad * 4 + rr;
    #pragma unroll
    for (int jd = 0; jd < 4; ++jd)
      O[rowbase + (size_t)trow * D_ + jd * 16 + ml] = f2b(acco[jd][rr] * inv);
  }
}

// ---------------- pooling (split for parallelism) ----------------
__global__ __launch_bounds__(256) void pool1_kernel(const float* __restrict__ x2, float* __restrict__ part) {
  int tc = blockIdx.x & 15, bn = blockIdx.x >> 4;
  int d = threadIdx.x;
  const float* base = x2 + ((size_t)bn * T_ + tc * 32) * D_;
  float s0 = 0.f, s1 = 0.f;
  for (int t = 0; t < 32; ++t) {
    s0 += base[(size_t)t * D_ + d];
    s1 += base[(size_t)t * D_ + d + 256];
  }
  float* p = part + ((size_t)bn * 16 + tc) * D_;
  p[d] = s0; p[d + 256] = s1;
}
__global__ __launch_bounds__(256) void pool2_kernel(const float* __restrict__ part, float* __restrict__ cp) {
  int bn = blockIdx.x;
  int d = threadIdx.x;
  float s0 = 0.f, s1 = 0.f;
  for (int tc = 0; tc < 16; ++tc) {
    s0 += part[((size_t)bn * 16 + tc) * D_ + d];
    s1 += part[((size_t)bn * 16 + tc) * D_ + d + 256];
  }
  cp[(size_t)bn * D_ + d]       = s0 * (1.f / T_);
  cp[(size_t)bn * D_ + d + 256] = s1 * (1.f / T_);
}

__global__ __launch_bounds__(256) void commit_center_kernel(
    const float* __restrict__ cp, const float* __restrict__ commit_w, const float* __restrict__ commit_b,
    const float* __restrict__ center_w, const float* __restrict__ center_b,
    float* __restrict__ commit, float* __restrict__ center) {
  __shared__ float cps[512];
  __shared__ float red[256];
  int bn = blockIdx.x, n = bn % N_, tid = threadIdx.x;
  cps[tid] = cp[(size_t)bn * D_ + tid];
  cps[tid + 256] = cp[(size_t)bn * D_ + tid + 256];
  __syncthreads();
  red[tid] = cps[tid] * commit_w[n * D_ + tid] + cps[tid + 256] * commit_w[n * D_ + tid + 256];
  __syncthreads();
  for (int s = 128; s > 0; s >>= 1) { if (tid < s) red[tid] += red[tid + s]; __syncthreads(); }
  if (tid == 0) commit[bn] = 1.f / (1.f + expf(-(red[0] + commit_b[n])));
  #pragma unroll
  for (int eo = 0; eo < 2; ++eo) {
    int e = eo * 256 + tid;
    float acc = center_b[(size_t)n * DC_ + e];
    for (int d = 0; d < D_; ++d) acc = fmaf(cps[d], center_w[((size_t)n * D_ + d) * DC_ + e], acc);
    center[(size_t)bn * DC_ + e] = tanhf(acc);
  }
}

__global__ __launch_bounds__(256) void matvec_kernel(
    const float* __restrict__ inp, const float* __restrict__ Wm, float* __restrict__ outp) {
  __shared__ float s[512];
  int bn = blockIdx.x, tid = threadIdx.x;
  s[tid] = inp[(size_t)bn * D_ + tid];
  s[tid + 256] = inp[(size_t)bn * D_ + tid + 256];
  __syncthreads();
  #pragma unroll
  for (int eo = 0; eo < 2; ++eo) {
    int e = eo * 256 + tid;
    float acc = 0.f;
    for (int d = 0; d < D_; ++d) acc = fmaf(s[d], Wm[(size_t)d * D_ + e], acc);
    outp[(size_t)bn * D_ + e] = acc;
  }
}

__global__ __launch_bounds__(256) void uv_kernel(
    const float* __restrict__ hres, float* __restrict__ u, float* __restrict__ v) {
  int i = blockIdx.x * 256 + threadIdx.x;
  float xr = hres[2 * i] + PR_EPS;
  float yi = hres[2 * i + 1] + PR_EPS;
  float r = sqrtf(xr * xr + yi * yi);
  u[i] = xr / r; v[i] = yi / r;
}

__global__ __launch_bounds__(256) void racc_kernel(
    const float* __restrict__ u, const float* __restrict__ v, float* __restrict__ ra) {
  int b = blockIdx.x, tid = threadIdx.x;
  int mm = tid >> 4, nn = tid & 15;
  const float* ub = u + (size_t)b * N_ * 256;
  const float* vb = v + (size_t)b * N_ * 256;
  float acc = 0.f;
  for (int p = 0; p < 256; ++p)
    acc += ub[mm * 256 + p] * ub[nn * 256 + p] + vb[mm * 256 + p] * vb[nn * 256 + p];
  ra[(size_t)b * N_ * N_ + mm * N_ + nn] = acc * (1.f / 256.f);
}

__global__ __launch_bounds__(256) void recv_kernel(
    const float* __restrict__ ra, const float* __restrict__ commit,
    const float* __restrict__ hres, const float* __restrict__ cond, float* __restrict__ recv) {
  int bn = blockIdx.x, b = bn / N_, mm = bn % N_, tid = threadIdx.x;
  float c = cond[0];
  #pragma unroll
  for (int eo = 0; eo < 2; ++eo) {
    int d = eo * 256 + tid;
    float acc = 0.f;
    for (int nn = 0; nn < N_; ++nn)
      acc += ra[(size_t)b * N_ * N_ + mm * N_ + nn] * commit[b * N_ + nn] *
             hres[((size_t)b * N_ + nn) * D_ + d];
    recv[(size_t)bn * D_ + d] = c * acc;
  }
}

__global__ __launch_bounds__(256) void final_kernel(
    const float* __restrict__ x2, const float* __restrict__ commit,
    const float* __restrict__ gate, const u16* __restrict__ ff,
    const float* __restrict__ fs, float* __restrict__ out) {
  long long i4 = (long long)blockIdx.x * 256 + threadIdx.x;
  long long base = i4 * 4;
  int d = (int)(base & (D_ - 1));
  int t = (int)((base >> 9) & (T_ - 1));
  int bn = (int)(base >> 18);
  float cg = commit[bn] * gate[(size_t)bn * T_ + t];
  float4 xv = *(const float4*)(x2 + base);
  ushort4 fv = *(const ushort4*)(ff + base);
  float4 sv = *(const float4*)(fs + (size_t)bn * D_ + d);
  float4 r;
  r.x = xv.x + cg * b2f(fv.x) + sv.x;
  r.y = xv.y + cg * b2f(fv.y) + sv.y;
  r.z = xv.z + cg * b2f(fv.z) + sv.z;
  r.w = xv.w + cg * b2f(fv.w) + sv.w;
  *(float4*)(out + base) = r;
}

extern "C" void kernel_launch(void* const* d_in, const int* in_sizes, int n_in,
                              void* d_out, int out_size, void* d_ws, size_t ws_size,
                              hipStream_t stream) {
  (void)in_sizes; (void)n_in; (void)out_size;
  const float* x          = (const float*)d_in[0];
  const float* gate_w     = (const float*)d_in[1];
  const float* gate_b     = (const float*)d_in[2];
  const float* ln1_g      = (const float*)d_in[3];
  const float* ln1_b      = (const float*)d_in[4];
  const float* wq         = (const float*)d_in[5];
  const float* wk         = (const float*)d_in[6];
  const float* wv         = (const float*)d_in[7];
  const float* wo         = (const float*)d_in[8];
  const float* phase      = (const float*)d_in[9];
  const float* ln2_g      = (const float*)d_in[10];
  const float* ln2_b      = (const float*)d_in[11];
  const float* up_w       = (const float*)d_in[12];
  const float* up_b       = (const float*)d_in[13];
  const float* down_w     = (const float*)d_in[14];
  const float* down_b     = (const float*)d_in[15];
  const float* commit_w   = (const float*)d_in[16];
  const float* commit_b   = (const float*)d_in[17];
  const float* center_w   = (const float*)d_in[18];
  const float* center_b   = (const float*)d_in[19];
  const float* field_in_w = (const float*)d_in[20];
  const float* field_out_w= (const float*)d_in[21];
  const float* cond       = (const float*)d_in[22];

  const long long BNTD = 8388608LL;     // 2*16*512*512
  u16* w16 = (u16*)d_ws;
  u16* R0 = w16;               // h -> attnout -> ff
  u16* R1 = w16 + BNTD;        // Q -> h2
  u16* R2 = w16 + 2 * BNTD;    // K -> up (stride 832, spills into R3)
  u16* R3 = w16 + 3 * BNTD;    // V
  float* sm   = (float*)(w16 + 4 * BNTD);
  float* gate   = sm;
  float* cp     = sm + 16384;
  float* center = sm + 2 * 16384;
  float* hres   = sm + 3 * 16384;
  float* uu     = sm + 4 * 16384;
  float* vv     = uu + 8192;
  float* ra     = vv + 8192;
  float* recvb  = ra + 512;
  float* fsig   = recvb + 16384;
  float* commit = fsig + 16384;
  float* part   = sm + 115232;           // 32*16*512 f32 = 262144
  float* x2 = (float*)d_out;

  // ---- converted weights (bf16 transposed) + Vt in ws tail ----
  const size_t WSQ = (size_t)N_ * 512 * 512;
  const size_t WUPu = (size_t)N_ * 828 * 512;
  const size_t WUPd = (size_t)N_ * 512 * 832;
  u16* wtbase = (u16*)(sm + 115232 + 262144);
  u16* wtq = wtbase;
  u16* wtk = wtq + WSQ;
  u16* wtv = wtk + WSQ;
  u16* wto = wtv + WSQ;
  u16* wtu = wto + WSQ;
  u16* wtd = wtu + WUPu;
  u16* vtb = wtd + WUPd;                 // Vt: [bn*8+h][64][512] u16
  size_t needed = (size_t)((char*)(vtb + BNTD) - (char*)d_ws);
  bool use_wt = ws_size >= needed;

  ln_gate_kernel<<<16384, 256, 0, stream>>>(x, gate_w, gate_b, ln1_g, ln1_b, gate, R0, 1);

  if (use_wt) {
    wconv_kernel<<<dim3(16, 16, 16), 256, 0, stream>>>(wq, wtq, 512, 512, 512);
    wconv_kernel<<<dim3(16, 16, 16), 256, 0, stream>>>(wk, wtk, 512, 512, 512);
    wconv_kernel<<<dim3(16, 16, 16), 256, 0, stream>>>(wv, wtv, 512, 512, 512);
    wconv_kernel<<<dim3(16, 16, 16), 256, 0, stream>>>(wo, wto, 512, 512, 512);
    wconv_kernel<<<dim3(26, 16, 16), 256, 0, stream>>>(up_w, wtu, 512, 828, 512);
    wconv_kernel<<<dim3(16, 26, 16), 256, 0, stream>>>(down_w, wtd, 828, 512, 832);
  }
  const u16* pq = use_wt ? wtq : nullptr;
  const u16* pk = use_wt ? wtk : nullptr;
  const u16* pv = use_wt ? wtv : nullptr;
  const u16* po = use_wt ? wto : nullptr;
  const u16* pu = use_wt ? wtu : nullptr;
  const u16* pd = use_wt ? wtd : nullptr;

  // fused QKV + rotation/gate (xdim=4, nXY=16, z=96 -> zPerXcd=12)
  gemm_mfma_kernel<<<1536, 256, 0, stream>>>(
      R0, wq, wk, wv, pq, pk, pv, R1, R2, R3, nullptr,
      512, 512, 512, 512, 0, nullptr, nullptr, gate, phase, 1, 4, 16, 12);
  if (use_wt) vtrans_kernel<<<dim3(16, 2, 256), 256, 0, stream>>>(R3, vtb);
  attn_kernel<<<dim3(8, 8, 32), 256, 0, stream>>>(R1, R2, R3, use_wt ? vtb : nullptr, R0);
  gemm_mfma_kernel<<<512, 256, 0, stream>>>(
      R0, wo, nullptr, nullptr, po, nullptr, nullptr, nullptr, nullptr, nullptr, x2,
      512, 512, 512, 512, 1, nullptr, x, gate, nullptr, 0, 4, 16, 4);
  ln_gate_kernel<<<16384, 256, 0, stream>>>(x2, nullptr, nullptr, ln2_g, ln2_b, nullptr, R1, 0);
  gemm_mfma_kernel<<<896, 256, 0, stream>>>(
      R1, up_w, nullptr, nullptr, pu, nullptr, nullptr, R2, nullptr, nullptr, nullptr,
      512, 512, 828, 832, 2, up_b, nullptr, nullptr, nullptr, 0, 7, 28, 4);
  gemm_mfma_kernel<<<512, 256, 0, stream>>>(
      R2, down_w, nullptr, nullptr, pd, nullptr, nullptr, R0, nullptr, nullptr, nullptr,
      832, 828, 512, 512, 3, down_b, nullptr, nullptr, nullptr, 0, 4, 16, 4);
  pool1_kernel<<<512, 256, 0, stream>>>(x2, part);
  pool2_kernel<<<32, 256, 0, stream>>>(part, cp);
  commit_center_kernel<<<32, 256, 0, stream>>>(cp, commit_w, commit_b, center_w, center_b, commit, center);
  matvec_kernel<<<32, 256, 0, stream>>>(center, field_in_w, hres);
  uv_kernel<<<32, 256, 0, stream>>>(hres, uu, vv);
  racc_kernel<<<2, 256, 0, stream>>>(uu, vv, ra);
  recv_kernel<<<32, 256, 0, stream>>>(ra, commit, hres, cond, recvb);
  matvec_kernel<<<32, 256, 0, stream>>>(recvb, field_out_w, fsig);
  final_kernel<<<8192, 256, 0, stream>>>(x2, commit, gate, R0, fsig, x2);
}